// Round 4
// baseline (308.790 us; speedup 1.0000x reference)
//
#include <hip/hip_runtime.h>
#include <math.h>

// ---------------- conv1: (512,1,32,32) -> conv3x3(32ch) -> BN -> ReLU -> pool2 -> h1 (512,32,15,15)
__global__ __launch_bounds__(256) void conv1_k(
    const float* __restrict__ x, const float* __restrict__ w,
    const float* __restrict__ cb, const float* __restrict__ bg,
    const float* __restrict__ bb, const float* __restrict__ bm,
    const float* __restrict__ bv, float* __restrict__ h1)
{
    __shared__ float img[1024];
    __shared__ float ws_[288];
    __shared__ float scale[32], bias2[32];
    const int b = blockIdx.x, tid = threadIdx.x;
    for (int i = tid; i < 1024; i += 256) img[i] = x[b * 1024 + i];
    for (int i = tid; i < 288; i += 256) ws_[i] = w[i];   // FIX: was `if (tid < 288)` with 256 threads
    if (tid < 32) {
        float inv = bg[tid] / sqrtf(bv[tid] + 1e-5f);
        scale[tid] = inv;
        bias2[tid] = (cb[tid] - bm[tid]) * inv + bb[tid];
    }
    __syncthreads();
    for (int e = tid; e < 7200; e += 256) {
        const int c = e / 225, r = e % 225;
        const int py = r / 15, px = r % 15;
        const int y0 = py * 2, x0 = px * 2;
        const float* wc = &ws_[c * 9];
        float p[4][4];
        for (int i = 0; i < 4; ++i)
            for (int j = 0; j < 4; ++j)
                p[i][j] = img[(y0 + i) * 32 + (x0 + j)];
        const float sc = scale[c], bs = bias2[c];
        float acc = 0.f;
        for (int dy = 0; dy < 2; ++dy)
            for (int dx = 0; dx < 2; ++dx) {
                float s = 0.f;
                for (int ky = 0; ky < 3; ++ky)
                    for (int kx = 0; kx < 3; ++kx)
                        s += p[dy + ky][dx + kx] * wc[ky * 3 + kx];
                acc += fmaxf(s * sc + bs, 0.f);
            }
        h1[b * 7200 + e] = acc * 0.25f;
    }
}

// ---------------- conv2: h1 (512,32,15,15) -> conv3x3(32ch) -> BN -> ReLU -> pool2 -> h2 (512,32,6,6)
__global__ __launch_bounds__(256) void conv2_k(
    const float* __restrict__ h1, const float* __restrict__ w,
    const float* __restrict__ cb, const float* __restrict__ bg,
    const float* __restrict__ bb, const float* __restrict__ bm,
    const float* __restrict__ bv, float* __restrict__ h2)
{
    __shared__ float in_s[7200];
    __shared__ float scale[32], bias2[32];
    const int b = blockIdx.x, tid = threadIdx.x;
    for (int i = tid; i < 7200; i += 256) in_s[i] = h1[b * 7200 + i];
    if (tid < 32) {
        float inv = bg[tid] / sqrtf(bv[tid] + 1e-5f);
        scale[tid] = inv;
        bias2[tid] = (cb[tid] - bm[tid]) * inv + bb[tid];
    }
    __syncthreads();
    for (int e = tid; e < 1152; e += 256) {
        const int co = e / 36, r = e % 36;
        const int py = r / 6, px = r % 6;
        const int y0 = py * 2, x0 = px * 2;
        float s00 = 0.f, s01 = 0.f, s10 = 0.f, s11 = 0.f;
        const float* wco = &w[co * 288];
        for (int ci = 0; ci < 32; ++ci) {
            const float* ip = &in_s[ci * 225 + y0 * 15 + x0];
            float p[4][4];
            for (int i = 0; i < 4; ++i)
                for (int j = 0; j < 4; ++j)
                    p[i][j] = ip[i * 15 + j];
            const float* wp = &wco[ci * 9];
            for (int ky = 0; ky < 3; ++ky)
                for (int kx = 0; kx < 3; ++kx) {
                    const float wv = wp[ky * 3 + kx];
                    s00 += p[ky][kx] * wv;
                    s01 += p[ky][kx + 1] * wv;
                    s10 += p[ky + 1][kx] * wv;
                    s11 += p[ky + 1][kx + 1] * wv;
                }
        }
        const float sc = scale[co], bs = bias2[co];
        float acc = fmaxf(s00 * sc + bs, 0.f) + fmaxf(s01 * sc + bs, 0.f)
                  + fmaxf(s10 * sc + bs, 0.f) + fmaxf(s11 * sc + bs, 0.f);
        h2[b * 1152 + e] = acc * 0.25f;
    }
}

// ---------------- conv3: h2 (512,32,6,6) -> conv3x3(32ch) -> BN -> ReLU -> pool2 -> feat (512,128)
__global__ __launch_bounds__(128) void conv3_k(
    const float* __restrict__ h2, const float* __restrict__ w,
    const float* __restrict__ cb, const float* __restrict__ bg,
    const float* __restrict__ bb, const float* __restrict__ bm,
    const float* __restrict__ bv, float* __restrict__ feat)
{
    __shared__ float in_s[1152];
    __shared__ float scale[32], bias2[32];
    const int b = blockIdx.x, tid = threadIdx.x;
    for (int i = tid; i < 1152; i += 128) in_s[i] = h2[b * 1152 + i];
    if (tid < 32) {
        float inv = bg[tid] / sqrtf(bv[tid] + 1e-5f);
        scale[tid] = inv;
        bias2[tid] = (cb[tid] - bm[tid]) * inv + bb[tid];
    }
    __syncthreads();
    const int co = tid >> 2, r = tid & 3;
    const int y0 = (r >> 1) * 2, x0 = (r & 1) * 2;
    float s00 = 0.f, s01 = 0.f, s10 = 0.f, s11 = 0.f;
    const float* wco = &w[co * 288];
    for (int ci = 0; ci < 32; ++ci) {
        const float* ip = &in_s[ci * 36 + y0 * 6 + x0];
        float p[4][4];
        for (int i = 0; i < 4; ++i)
            for (int j = 0; j < 4; ++j)
                p[i][j] = ip[i * 6 + j];
        const float* wp = &wco[ci * 9];
        for (int ky = 0; ky < 3; ++ky)
            for (int kx = 0; kx < 3; ++kx) {
                const float wv = wp[ky * 3 + kx];
                s00 += p[ky][kx] * wv;
                s01 += p[ky][kx + 1] * wv;
                s10 += p[ky + 1][kx] * wv;
                s11 += p[ky + 1][kx + 1] * wv;
            }
    }
    const float sc = scale[co], bs = bias2[co];
    float acc = fmaxf(s00 * sc + bs, 0.f) + fmaxf(s01 * sc + bs, 0.f)
              + fmaxf(s10 * sc + bs, 0.f) + fmaxf(s11 * sc + bs, 0.f);
    feat[b * 128 + tid] = acc * 0.25f;
}

// ---------------- E2[o][j] = (emb[o] @ Wxh)[j] + bh[j]
__global__ __launch_bounds__(384) void e2_k(
    const float* __restrict__ emb, const float* __restrict__ Wxh,
    const float* __restrict__ bh, float* __restrict__ E2)
{
    const int t = threadIdx.x;
    if (t < 384) {
        const int o = t >> 7, j = t & 127;
        float a = bh[j];
        for (int d = 0; d < 128; ++d) a += emb[o * 128 + d] * Wxh[d * 128 + j];
        E2[t] = a;
    }
}

// ---------------- router + beam search + expert chain + output log_softmax
// one block (256 threads) per sample
__global__ __launch_bounds__(256) void router_k(
    const float* __restrict__ feat, const float* __restrict__ Whh,
    const float* __restrict__ Who, const float* __restrict__ bo,
    const float* __restrict__ E2, const float* __restrict__ Wexp,
    const float* __restrict__ bexp, const float* __restrict__ Wout,
    const float* __restrict__ bout, float* __restrict__ out)
{
    const int b = blockIdx.x, tid = threadIdx.x;
    __shared__ float fs[128];
    __shared__ float hbuf[2][8][128];
    __shared__ float E2s[384];
    __shared__ float total[24];
    __shared__ float scores[8];
    __shared__ int bi[8];
    __shared__ int opsel[8];
    __shared__ int oph[3][8];
    __shared__ int oph2[3][8];
    __shared__ float l10[8][10];
    __shared__ float lsebuf[8];

    if (tid < 128) fs[tid] = feat[b * 128 + tid];
    for (int i = tid; i < 384; i += 256) E2s[i] = E2[i];
    if (tid < 8) scores[tid] = (tid == 0) ? 0.f : -1.0e9f;
    __syncthreads();
    {
        float* h0 = &hbuf[0][0][0];
        for (int i = tid; i < 1024; i += 256) h0[i] = fs[i & 127];
    }
    __syncthreads();

    int cur = 0;
    for (int t = 0; t < 3; ++t) {
        // ---- logits = hr @ Who + bo ; logp = log_softmax(logits/0.4) ; total = score + logp
        {
            const int g = tid >> 5, l = tid & 31;
            float p0 = 0.f, p1 = 0.f, p2 = 0.f;
            for (int d = l; d < 128; d += 32) {
                const float h = hbuf[cur][g][d];
                p0 += h * Who[d * 3 + 0];
                p1 += h * Who[d * 3 + 1];
                p2 += h * Who[d * 3 + 2];
            }
            for (int s = 16; s > 0; s >>= 1) {
                p0 += __shfl_down(p0, s, 32);
                p1 += __shfl_down(p1, s, 32);
                p2 += __shfl_down(p2, s, 32);
            }
            if (l == 0) {
                const float t0 = (p0 + bo[0]) / 0.4f;
                const float t1 = (p1 + bo[1]) / 0.4f;
                const float t2 = (p2 + bo[2]) / 0.4f;
                const float mm = fmaxf(t0, fmaxf(t1, t2));
                const float lse = mm + logf(expf(t0 - mm) + expf(t1 - mm) + expf(t2 - mm));
                const float sc = scores[g];
                total[g * 3 + 0] = sc + (t0 - lse);
                total[g * 3 + 1] = sc + (t1 - lse);
                total[g * 3 + 2] = sc + (t2 - lse);
            }
        }
        __syncthreads();
        // ---- stable top-8 (first-index-wins on ties, matches lax.top_k)
        if (tid == 0) {
            for (int r = 0; r < 8; ++r) {
                float best = -INFINITY; int idx = 0;
                for (int i = 0; i < 24; ++i) {
                    const float vv = total[i];
                    if (vv > best) { best = vv; idx = i; }
                }
                total[idx] = -INFINITY;
                scores[r] = best;
                bi[r] = idx / 3;
                opsel[r] = idx % 3;
            }
            // gather op history through beam reordering
            for (int r = 0; r < 8; ++r) {
                for (int s = 0; s < t; ++s) oph2[s][r] = oph[s][bi[r]];
                oph2[t][r] = opsel[r];
            }
            for (int r = 0; r < 8; ++r)
                for (int s = 0; s <= t; ++s) oph[s][r] = oph2[s][r];
        }
        __syncthreads();
        // ---- hr = tanh(hr[beam_idx] @ Whh + E2[op])
        {
            const int j = tid & 127, half = tid >> 7;
            const int n0 = half, n1 = half + 2, n2 = half + 4, n3 = half + 6;
            float a0 = E2s[opsel[n0] * 128 + j];
            float a1 = E2s[opsel[n1] * 128 + j];
            float a2 = E2s[opsel[n2] * 128 + j];
            float a3 = E2s[opsel[n3] * 128 + j];
            const float* r0 = hbuf[cur][bi[n0]];
            const float* r1 = hbuf[cur][bi[n1]];
            const float* r2 = hbuf[cur][bi[n2]];
            const float* r3 = hbuf[cur][bi[n3]];
            for (int d = 0; d < 128; ++d) {
                const float wv = Whh[d * 128 + j];
                a0 += r0[d] * wv;
                a1 += r1[d] * wv;
                a2 += r2[d] * wv;
                a3 += r3[d] * wv;
            }
            const int nxt = cur ^ 1;
            hbuf[nxt][n0][j] = tanhf(a0);
            hbuf[nxt][n1][j] = tanhf(a1);
            hbuf[nxt][n2][j] = tanhf(a2);
            hbuf[nxt][n3][j] = tanhf(a3);
        }
        cur ^= 1;
        __syncthreads();
    }

    // ---- expert chain: hs = feat broadcast; hs = relu(hs @ Wexp[o] + bexp[o]) x3
    {
        float* h0 = &hbuf[0][0][0];
        for (int i = tid; i < 1024; i += 256) h0[i] = fs[i & 127];
    }
    __syncthreads();
    int c2 = 0;
    for (int t = 0; t < 3; ++t) {
        const int j = tid & 127, half = tid >> 7;
        const int n0 = half, n1 = half + 2, n2 = half + 4, n3 = half + 6;
        const int o0 = oph[t][n0], o1 = oph[t][n1], o2 = oph[t][n2], o3 = oph[t][n3];
        float a0 = bexp[o0 * 128 + j];
        float a1 = bexp[o1 * 128 + j];
        float a2 = bexp[o2 * 128 + j];
        float a3 = bexp[o3 * 128 + j];
        const float* r0 = hbuf[c2][n0];
        const float* r1 = hbuf[c2][n1];
        const float* r2 = hbuf[c2][n2];
        const float* r3 = hbuf[c2][n3];
        const float* w0 = &Wexp[o0 * 16384 + j];
        const float* w1 = &Wexp[o1 * 16384 + j];
        const float* w2 = &Wexp[o2 * 16384 + j];
        const float* w3 = &Wexp[o3 * 16384 + j];
        for (int d = 0; d < 128; ++d) {
            a0 += r0[d] * w0[d * 128];
            a1 += r1[d] * w1[d * 128];
            a2 += r2[d] * w2[d * 128];
            a3 += r3[d] * w3[d * 128];
        }
        const int nxt = c2 ^ 1;
        hbuf[nxt][n0][j] = fmaxf(a0, 0.f);
        hbuf[nxt][n1][j] = fmaxf(a1, 0.f);
        hbuf[nxt][n2][j] = fmaxf(a2, 0.f);
        hbuf[nxt][n3][j] = fmaxf(a3, 0.f);
        c2 ^= 1;
        __syncthreads();
    }

    // ---- out = log_softmax(hs @ Wout + bout)
    if (tid < 80) {
        const int nb = tid / 10, c = tid % 10;
        float acc = bout[c];
        const float* hrow = hbuf[c2][nb];
        for (int d = 0; d < 128; ++d) acc += hrow[d] * Wout[d * 10 + c];
        l10[nb][c] = acc;
    }
    __syncthreads();
    if (tid < 8) {
        float mm = l10[tid][0];
        for (int c = 1; c < 10; ++c) mm = fmaxf(mm, l10[tid][c]);
        float s = 0.f;
        for (int c = 0; c < 10; ++c) s += expf(l10[tid][c] - mm);
        lsebuf[tid] = mm + logf(s);
    }
    __syncthreads();
    if (tid < 80) {
        const int nb = tid / 10, c = tid % 10;
        out[(b * 8 + nb) * 10 + c] = l10[nb][c] - lsebuf[nb];
    }
}

extern "C" void kernel_launch(void* const* d_in, const int* in_sizes, int n_in,
                              void* d_out, int out_size, void* d_ws, size_t ws_size,
                              hipStream_t stream) {
    (void)in_sizes; (void)n_in; (void)out_size; (void)ws_size;
    const float* x    = (const float*)d_in[0];
    const float* c1w  = (const float*)d_in[1];
    const float* c1b  = (const float*)d_in[2];
    const float* g1   = (const float*)d_in[3];
    const float* b1   = (const float*)d_in[4];
    const float* m1   = (const float*)d_in[5];
    const float* v1   = (const float*)d_in[6];
    const float* c2w  = (const float*)d_in[7];
    const float* c2b  = (const float*)d_in[8];
    const float* g2   = (const float*)d_in[9];
    const float* b2   = (const float*)d_in[10];
    const float* m2   = (const float*)d_in[11];
    const float* v2   = (const float*)d_in[12];
    const float* c3w  = (const float*)d_in[13];
    const float* c3b  = (const float*)d_in[14];
    const float* g3   = (const float*)d_in[15];
    const float* b3   = (const float*)d_in[16];
    const float* m3   = (const float*)d_in[17];
    const float* v3   = (const float*)d_in[18];
    const float* Wxh  = (const float*)d_in[19];
    const float* Whh  = (const float*)d_in[20];
    const float* bh   = (const float*)d_in[21];
    const float* Who  = (const float*)d_in[22];
    const float* bo   = (const float*)d_in[23];
    const float* emb  = (const float*)d_in[24];
    const float* Wexp = (const float*)d_in[25];
    const float* bexp = (const float*)d_in[26];
    const float* Wout = (const float*)d_in[27];
    const float* bout = (const float*)d_in[28];

    float* ws   = (float*)d_ws;
    float* h1   = ws;                    // 512*7200 = 3,686,400
    float* h2   = h1 + 3686400;          // 512*1152 =   589,824
    float* feat = h2 + 589824;           // 512*128  =    65,536
    float* E2   = feat + 65536;          // 3*128    =       384

    e2_k<<<1, 384, 0, stream>>>(emb, Wxh, bh, E2);
    conv1_k<<<512, 256, 0, stream>>>(x, c1w, c1b, g1, b1, m1, v1, h1);
    conv2_k<<<512, 256, 0, stream>>>(h1, c2w, c2b, g2, b2, m2, v2, h2);
    conv3_k<<<512, 128, 0, stream>>>(h2, c3w, c3b, g3, b3, m3, v3, feat);
    router_k<<<512, 256, 0, stream>>>(feat, Whh, Who, bo, E2, Wexp, bexp, Wout, bout,
                                      (float*)d_out);
}

// Round 5
// 246.917 us; speedup vs baseline: 1.2506x; 1.2506x over previous
//
#include <hip/hip_runtime.h>
#include <math.h>

// ---------------- conv1: (512,1,32,32) -> conv3x3(32ch) -> BN -> ReLU -> pool2 -> h1 (512,32,15,15)
// Thread layout: co = tid>>4 (0..31), py = tid&15 (rows 0..14 active).
// All input reads are wave-broadcast (16 rows -> 16 distinct banks via stride-33 pad).
__global__ __launch_bounds__(512) void conv1_k(
    const float* __restrict__ x, const float* __restrict__ w,
    const float* __restrict__ cb, const float* __restrict__ bg,
    const float* __restrict__ bb, const float* __restrict__ bm,
    const float* __restrict__ bv, float* __restrict__ h1)
{
    __shared__ float img[32 * 33];            // row stride 33: bank = (2*py + c) % 32, 16 rows distinct
    __shared__ float ws_[288];
    __shared__ float scale[32], bias2[32];
    const int b = blockIdx.x, tid = threadIdx.x;
    for (int i = tid; i < 1024; i += 512) {
        const int y = i >> 5, xx = i & 31;
        img[y * 33 + xx] = x[b * 1024 + i];
    }
    if (tid < 288) ws_[tid] = w[tid];
    if (tid < 32) {
        float inv = bg[tid] / sqrtf(bv[tid] + 1e-5f);
        scale[tid] = inv;
        bias2[tid] = (cb[tid] - bm[tid]) * inv + bb[tid];
    }
    __syncthreads();

    const int co = tid >> 4, py = tid & 15;
    if (py < 15) {
        float acc0[30], acc1[30];
        #pragma unroll
        for (int i = 0; i < 30; ++i) { acc0[i] = 0.f; acc1[i] = 0.f; }
        const float* w9 = &ws_[co * 9];
        #pragma unroll
        for (int ir = 0; ir < 4; ++ir) {
            const int y = 2 * py + ir;
            float wk0 = 0.f, wk1 = 0.f, wk2 = 0.f, wl0 = 0.f, wl1 = 0.f, wl2 = 0.f;
            if (ir <= 2) { wk0 = w9[ir * 3 + 0]; wk1 = w9[ir * 3 + 1]; wk2 = w9[ir * 3 + 2]; }
            if (ir >= 1) { wl0 = w9[(ir - 1) * 3 + 0]; wl1 = w9[(ir - 1) * 3 + 1]; wl2 = w9[(ir - 1) * 3 + 2]; }
            #pragma unroll
            for (int xx = 0; xx < 32; ++xx) {
                const float rv = img[y * 33 + xx];
                if (ir <= 2) {
                    if (xx <= 29) acc0[xx] += rv * wk0;
                    if (xx >= 1 && xx <= 30) acc0[xx - 1] += rv * wk1;
                    if (xx >= 2) acc0[xx - 2] += rv * wk2;
                }
                if (ir >= 1) {
                    if (xx <= 29) acc1[xx] += rv * wl0;
                    if (xx >= 1 && xx <= 30) acc1[xx - 1] += rv * wl1;
                    if (xx >= 2) acc1[xx - 2] += rv * wl2;
                }
            }
        }
        const float sc = scale[co], bs = bias2[co];
        #pragma unroll
        for (int px = 0; px < 15; ++px) {
            const float v = fmaxf(acc0[2 * px] * sc + bs, 0.f)
                          + fmaxf(acc0[2 * px + 1] * sc + bs, 0.f)
                          + fmaxf(acc1[2 * px] * sc + bs, 0.f)
                          + fmaxf(acc1[2 * px + 1] * sc + bs, 0.f);
            h1[b * 7200 + co * 225 + py * 15 + px] = v * 0.25f;
        }
    }
}

// ---------------- conv2: h1 (512,32,15,15) -> conv3x3(32ch) -> BN -> ReLU -> pool2 -> h2 (512,32,6,6)
// Thread layout: co = tid&31, g = tid>>5 (0..11): py = g>>1 (0..5), xh = g&1.
// Input reads: wave-broadcast (2 addrs/wave). Weight reads: w_s[k*32+co], stride-1 in co -> conflict-free.
__global__ __launch_bounds__(384) void conv2_k(
    const float* __restrict__ h1, const float* __restrict__ w,
    const float* __restrict__ cb, const float* __restrict__ bg,
    const float* __restrict__ bb, const float* __restrict__ bm,
    const float* __restrict__ bv, float* __restrict__ h2)
{
    __shared__ float in_s[32 * 210];          // rows 0..13 only (row 14 unused), 6720 floats
    __shared__ float w_s[9216];               // transposed: w_s[k*32 + co], k = ci*9 + kk
    __shared__ float scale[32], bias2[32];
    const int b = blockIdx.x, tid = threadIdx.x;
    for (int i = tid; i < 6720; i += 384) {
        const int ci = i / 210, rem = i % 210;
        in_s[i] = h1[b * 7200 + ci * 225 + rem];
    }
    for (int i = tid; i < 9216; i += 384) {
        const int co = i & 31, k = i >> 5;
        w_s[i] = w[co * 288 + k];             // linear LDS write; gather from L2-hot weights
    }
    if (tid < 32) {
        float inv = bg[tid] / sqrtf(bv[tid] + 1e-5f);
        scale[tid] = inv;
        bias2[tid] = (cb[tid] - bm[tid]) * inv + bb[tid];
    }
    __syncthreads();

    const int co = tid & 31, g = tid >> 5;
    const int py = g >> 1, xh = g & 1;        // py 0..5, xh 0..1
    const int gx0 = xh * 6;                   // input col base; cols gx0..gx0+7
    float acc0[6], acc1[6];
    #pragma unroll
    for (int i = 0; i < 6; ++i) { acc0[i] = 0.f; acc1[i] = 0.f; }

    for (int ci = 0; ci < 32; ++ci) {
        float w9[9];
        #pragma unroll
        for (int kk = 0; kk < 9; ++kk) w9[kk] = w_s[(ci * 9 + kk) * 32 + co];
        const float* ip = &in_s[ci * 210];
        #pragma unroll
        for (int ir = 0; ir < 4; ++ir) {
            const int y = 2 * py + ir;        // <= 13
            const float* rowp = &ip[y * 15 + gx0];
            #pragma unroll
            for (int xx = 0; xx < 8; ++xx) {
                const float rv = rowp[xx];
                if (ir <= 2) {
                    if (xx <= 5) acc0[xx] += rv * w9[ir * 3 + 0];
                    if (xx >= 1 && xx <= 6) acc0[xx - 1] += rv * w9[ir * 3 + 1];
                    if (xx >= 2) acc0[xx - 2] += rv * w9[ir * 3 + 2];
                }
                if (ir >= 1) {
                    if (xx <= 5) acc1[xx] += rv * w9[(ir - 1) * 3 + 0];
                    if (xx >= 1 && xx <= 6) acc1[xx - 1] += rv * w9[(ir - 1) * 3 + 1];
                    if (xx >= 2) acc1[xx - 2] += rv * w9[(ir - 1) * 3 + 2];
                }
            }
        }
    }
    const float sc = scale[co], bs = bias2[co];
    #pragma unroll
    for (int pxl = 0; pxl < 3; ++pxl) {
        const float v = fmaxf(acc0[2 * pxl] * sc + bs, 0.f)
                      + fmaxf(acc0[2 * pxl + 1] * sc + bs, 0.f)
                      + fmaxf(acc1[2 * pxl] * sc + bs, 0.f)
                      + fmaxf(acc1[2 * pxl + 1] * sc + bs, 0.f);
        h2[b * 1152 + co * 36 + py * 6 + xh * 3 + pxl] = v * 0.25f;
    }
}

// ---------------- conv3: h2 (512,32,6,6) -> conv3x3(32ch) -> BN -> ReLU -> pool2 -> feat (512,128)
__global__ __launch_bounds__(128) void conv3_k(
    const float* __restrict__ h2, const float* __restrict__ w,
    const float* __restrict__ cb, const float* __restrict__ bg,
    const float* __restrict__ bb, const float* __restrict__ bm,
    const float* __restrict__ bv, float* __restrict__ feat)
{
    __shared__ float in_s[1152];
    __shared__ float scale[32], bias2[32];
    const int b = blockIdx.x, tid = threadIdx.x;
    for (int i = tid; i < 1152; i += 128) in_s[i] = h2[b * 1152 + i];
    if (tid < 32) {
        float inv = bg[tid] / sqrtf(bv[tid] + 1e-5f);
        scale[tid] = inv;
        bias2[tid] = (cb[tid] - bm[tid]) * inv + bb[tid];
    }
    __syncthreads();
    const int co = tid >> 2, r = tid & 3;
    const int y0 = (r >> 1) * 2, x0 = (r & 1) * 2;
    float s00 = 0.f, s01 = 0.f, s10 = 0.f, s11 = 0.f;
    const float* wco = &w[co * 288];
    for (int ci = 0; ci < 32; ++ci) {
        const float* ip = &in_s[ci * 36 + y0 * 6 + x0];
        float p[4][4];
        for (int i = 0; i < 4; ++i)
            for (int j = 0; j < 4; ++j)
                p[i][j] = ip[i * 6 + j];
        const float* wp = &wco[ci * 9];
        for (int ky = 0; ky < 3; ++ky)
            for (int kx = 0; kx < 3; ++kx) {
                const float wv = wp[ky * 3 + kx];
                s00 += p[ky][kx] * wv;
                s01 += p[ky][kx + 1] * wv;
                s10 += p[ky + 1][kx] * wv;
                s11 += p[ky + 1][kx + 1] * wv;
            }
    }
    const float sc = scale[co], bs = bias2[co];
    float acc = fmaxf(s00 * sc + bs, 0.f) + fmaxf(s01 * sc + bs, 0.f)
              + fmaxf(s10 * sc + bs, 0.f) + fmaxf(s11 * sc + bs, 0.f);
    feat[b * 128 + tid] = acc * 0.25f;
}

// ---------------- E2[o][j] = (emb[o] @ Wxh)[j] + bh[j]
__global__ __launch_bounds__(384) void e2_k(
    const float* __restrict__ emb, const float* __restrict__ Wxh,
    const float* __restrict__ bh, float* __restrict__ E2)
{
    const int t = threadIdx.x;
    if (t < 384) {
        const int o = t >> 7, j = t & 127;
        float a = bh[j];
        for (int d = 0; d < 128; ++d) a += emb[o * 128 + d] * Wxh[d * 128 + j];
        E2[t] = a;
    }
}

// ---------------- router + beam search + expert chain + output log_softmax
// one block (256 threads) per sample
__global__ __launch_bounds__(256) void router_k(
    const float* __restrict__ feat, const float* __restrict__ Whh,
    const float* __restrict__ Who, const float* __restrict__ bo,
    const float* __restrict__ E2, const float* __restrict__ Wexp,
    const float* __restrict__ bexp, const float* __restrict__ Wout,
    const float* __restrict__ bout, float* __restrict__ out)
{
    const int b = blockIdx.x, tid = threadIdx.x;
    __shared__ float fs[128];
    __shared__ float hbuf[2][8][128];
    __shared__ float E2s[384];
    __shared__ float total[24];
    __shared__ float scores[8];
    __shared__ int bi[8];
    __shared__ int opsel[8];
    __shared__ int oph[3][8];
    __shared__ int oph2[3][8];
    __shared__ float l10[8][10];
    __shared__ float lsebuf[8];

    if (tid < 128) fs[tid] = feat[b * 128 + tid];
    for (int i = tid; i < 384; i += 256) E2s[i] = E2[i];
    if (tid < 8) scores[tid] = (tid == 0) ? 0.f : -1.0e9f;
    __syncthreads();
    {
        float* h0 = &hbuf[0][0][0];
        for (int i = tid; i < 1024; i += 256) h0[i] = fs[i & 127];
    }
    __syncthreads();

    int cur = 0;
    for (int t = 0; t < 3; ++t) {
        // ---- logits = hr @ Who + bo ; logp = log_softmax(logits/0.4) ; total = score + logp
        {
            const int g = tid >> 5, l = tid & 31;
            float p0 = 0.f, p1 = 0.f, p2 = 0.f;
            for (int d = l; d < 128; d += 32) {
                const float h = hbuf[cur][g][d];
                p0 += h * Who[d * 3 + 0];
                p1 += h * Who[d * 3 + 1];
                p2 += h * Who[d * 3 + 2];
            }
            for (int s = 16; s > 0; s >>= 1) {
                p0 += __shfl_down(p0, s, 32);
                p1 += __shfl_down(p1, s, 32);
                p2 += __shfl_down(p2, s, 32);
            }
            if (l == 0) {
                const float t0 = (p0 + bo[0]) / 0.4f;
                const float t1 = (p1 + bo[1]) / 0.4f;
                const float t2 = (p2 + bo[2]) / 0.4f;
                const float mm = fmaxf(t0, fmaxf(t1, t2));
                const float lse = mm + logf(expf(t0 - mm) + expf(t1 - mm) + expf(t2 - mm));
                const float sc = scores[g];
                total[g * 3 + 0] = sc + (t0 - lse);
                total[g * 3 + 1] = sc + (t1 - lse);
                total[g * 3 + 2] = sc + (t2 - lse);
            }
        }
        __syncthreads();
        // ---- stable top-8 (first-index-wins on ties, matches lax.top_k)
        if (tid == 0) {
            for (int r = 0; r < 8; ++r) {
                float best = -INFINITY; int idx = 0;
                for (int i = 0; i < 24; ++i) {
                    const float vv = total[i];
                    if (vv > best) { best = vv; idx = i; }
                }
                total[idx] = -INFINITY;
                scores[r] = best;
                bi[r] = idx / 3;
                opsel[r] = idx % 3;
            }
            // gather op history through beam reordering
            for (int r = 0; r < 8; ++r) {
                for (int s = 0; s < t; ++s) oph2[s][r] = oph[s][bi[r]];
                oph2[t][r] = opsel[r];
            }
            for (int r = 0; r < 8; ++r)
                for (int s = 0; s <= t; ++s) oph[s][r] = oph2[s][r];
        }
        __syncthreads();
        // ---- hr = tanh(hr[beam_idx] @ Whh + E2[op])
        {
            const int j = tid & 127, half = tid >> 7;
            const int n0 = half, n1 = half + 2, n2 = half + 4, n3 = half + 6;
            float a0 = E2s[opsel[n0] * 128 + j];
            float a1 = E2s[opsel[n1] * 128 + j];
            float a2 = E2s[opsel[n2] * 128 + j];
            float a3 = E2s[opsel[n3] * 128 + j];
            const float* r0 = hbuf[cur][bi[n0]];
            const float* r1 = hbuf[cur][bi[n1]];
            const float* r2 = hbuf[cur][bi[n2]];
            const float* r3 = hbuf[cur][bi[n3]];
            for (int d = 0; d < 128; ++d) {
                const float wv = Whh[d * 128 + j];
                a0 += r0[d] * wv;
                a1 += r1[d] * wv;
                a2 += r2[d] * wv;
                a3 += r3[d] * wv;
            }
            const int nxt = cur ^ 1;
            hbuf[nxt][n0][j] = tanhf(a0);
            hbuf[nxt][n1][j] = tanhf(a1);
            hbuf[nxt][n2][j] = tanhf(a2);
            hbuf[nxt][n3][j] = tanhf(a3);
        }
        cur ^= 1;
        __syncthreads();
    }

    // ---- expert chain: hs = feat broadcast; hs = relu(hs @ Wexp[o] + bexp[o]) x3
    {
        float* h0 = &hbuf[0][0][0];
        for (int i = tid; i < 1024; i += 256) h0[i] = fs[i & 127];
    }
    __syncthreads();
    int c2 = 0;
    for (int t = 0; t < 3; ++t) {
        const int j = tid & 127, half = tid >> 7;
        const int n0 = half, n1 = half + 2, n2 = half + 4, n3 = half + 6;
        const int o0 = oph[t][n0], o1 = oph[t][n1], o2 = oph[t][n2], o3 = oph[t][n3];
        float a0 = bexp[o0 * 128 + j];
        float a1 = bexp[o1 * 128 + j];
        float a2 = bexp[o2 * 128 + j];
        float a3 = bexp[o3 * 128 + j];
        const float* r0 = hbuf[c2][n0];
        const float* r1 = hbuf[c2][n1];
        const float* r2 = hbuf[c2][n2];
        const float* r3 = hbuf[c2][n3];
        const float* w0 = &Wexp[o0 * 16384 + j];
        const float* w1 = &Wexp[o1 * 16384 + j];
        const float* w2 = &Wexp[o2 * 16384 + j];
        const float* w3 = &Wexp[o3 * 16384 + j];
        for (int d = 0; d < 128; ++d) {
            a0 += r0[d] * w0[d * 128];
            a1 += r1[d] * w1[d * 128];
            a2 += r2[d] * w2[d * 128];
            a3 += r3[d] * w3[d * 128];
        }
        const int nxt = c2 ^ 1;
        hbuf[nxt][n0][j] = fmaxf(a0, 0.f);
        hbuf[nxt][n1][j] = fmaxf(a1, 0.f);
        hbuf[nxt][n2][j] = fmaxf(a2, 0.f);
        hbuf[nxt][n3][j] = fmaxf(a3, 0.f);
        c2 ^= 1;
        __syncthreads();
    }

    // ---- out = log_softmax(hs @ Wout + bout)
    if (tid < 80) {
        const int nb = tid / 10, c = tid % 10;
        float acc = bout[c];
        const float* hrow = hbuf[c2][nb];
        for (int d = 0; d < 128; ++d) acc += hrow[d] * Wout[d * 10 + c];
        l10[nb][c] = acc;
    }
    __syncthreads();
    if (tid < 8) {
        float mm = l10[tid][0];
        for (int c = 1; c < 10; ++c) mm = fmaxf(mm, l10[tid][c]);
        float s = 0.f;
        for (int c = 0; c < 10; ++c) s += expf(l10[tid][c] - mm);
        lsebuf[tid] = mm + logf(s);
    }
    __syncthreads();
    if (tid < 80) {
        const int nb = tid / 10, c = tid % 10;
        out[(b * 8 + nb) * 10 + c] = l10[nb][c] - lsebuf[nb];
    }
}

extern "C" void kernel_launch(void* const* d_in, const int* in_sizes, int n_in,
                              void* d_out, int out_size, void* d_ws, size_t ws_size,
                              hipStream_t stream) {
    (void)in_sizes; (void)n_in; (void)out_size; (void)ws_size;
    const float* x    = (const float*)d_in[0];
    const float* c1w  = (const float*)d_in[1];
    const float* c1b  = (const float*)d_in[2];
    const float* g1   = (const float*)d_in[3];
    const float* b1   = (const float*)d_in[4];
    const float* m1   = (const float*)d_in[5];
    const float* v1   = (const float*)d_in[6];
    const float* c2w  = (const float*)d_in[7];
    const float* c2b  = (const float*)d_in[8];
    const float* g2   = (const float*)d_in[9];
    const float* b2   = (const float*)d_in[10];
    const float* m2   = (const float*)d_in[11];
    const float* v2   = (const float*)d_in[12];
    const float* c3w  = (const float*)d_in[13];
    const float* c3b  = (const float*)d_in[14];
    const float* g3   = (const float*)d_in[15];
    const float* b3   = (const float*)d_in[16];
    const float* m3   = (const float*)d_in[17];
    const float* v3   = (const float*)d_in[18];
    const float* Wxh  = (const float*)d_in[19];
    const float* Whh  = (const float*)d_in[20];
    const float* bh   = (const float*)d_in[21];
    const float* Who  = (const float*)d_in[22];
    const float* bo   = (const float*)d_in[23];
    const float* emb  = (const float*)d_in[24];
    const float* Wexp = (const float*)d_in[25];
    const float* bexp = (const float*)d_in[26];
    const float* Wout = (const float*)d_in[27];
    const float* bout = (const float*)d_in[28];

    float* ws   = (float*)d_ws;
    float* h1   = ws;                    // 512*7200 = 3,686,400
    float* h2   = h1 + 3686400;          // 512*1152 =   589,824
    float* feat = h2 + 589824;           // 512*128  =    65,536
    float* E2   = feat + 65536;          // 3*128    =       384

    e2_k<<<1, 384, 0, stream>>>(emb, Wxh, bh, E2);
    conv1_k<<<512, 512, 0, stream>>>(x, c1w, c1b, g1, b1, m1, v1, h1);
    conv2_k<<<512, 384, 0, stream>>>(h1, c2w, c2b, g2, b2, m2, v2, h2);
    conv3_k<<<512, 128, 0, stream>>>(h2, c3w, c3b, g3, b3, m3, v3, feat);
    router_k<<<512, 256, 0, stream>>>(feat, Whh, Who, bo, E2, Wexp, bexp, Wout, bout,
                                      (float*)d_out);
}